// Round 1
// 203.349 us; speedup vs baseline: 1.0106x; 1.0106x over previous
//
#include <hip/hip_runtime.h>
#include <math.h>

#define PI_F 3.14159265358979323846f
#define TWO_PI_F 6.28318530717958647692f
#define RSQ2 0.70710678118654752440f

// wave-synchronous LDS fence: waits this wave's own DS ops; memory clobber
// stops the compiler from moving LDS accesses across it. Each wave owns a
// private LDS region, so no s_barrier is needed.
#define WAVE_SYNC() __asm__ volatile("s_waitcnt lgkmcnt(0)" ::: "memory")
// additive swizzle: injective on [0,512), max 574; breaks the 2-bank
// degeneracy of the stage-0 write pattern (8j+i).
#define LADDR(a) ((a) + ((a) >> 3))

__device__ __forceinline__ float2 cadd(float2 a, float2 b){ return make_float2(a.x+b.x, a.y+b.y); }
__device__ __forceinline__ float2 csub(float2 a, float2 b){ return make_float2(a.x-b.x, a.y-b.y); }
__device__ __forceinline__ float2 cmul(float2 a, float2 b){ return make_float2(a.x*b.x - a.y*b.y, a.x*b.y + a.y*b.x); }
__device__ __forceinline__ float2 cw1(float2 a){ return make_float2(RSQ2*(a.x+a.y), RSQ2*(a.y-a.x)); }  // *W8^1
__device__ __forceinline__ float2 cw2(float2 a){ return make_float2(a.y, -a.x); }                        // *(-i)
__device__ __forceinline__ float2 cw3(float2 a){ return make_float2(RSQ2*(a.y-a.x), -RSQ2*(a.x+a.y)); }  // *W8^3

// in-place DIF-8. On return, slot m holds U_{br[m]}, br = {0,4,2,6,1,5,3,7}.
__device__ __forceinline__ void dft8(float2* v){
    float2 a0=cadd(v[0],v[4]), a1=cadd(v[1],v[5]), a2=cadd(v[2],v[6]), a3=cadd(v[3],v[7]);
    float2 b0=csub(v[0],v[4]);
    float2 b1=cw1(csub(v[1],v[5]));
    float2 b2=cw2(csub(v[2],v[6]));
    float2 b3=cw3(csub(v[3],v[7]));
    float2 c0=cadd(a0,a2), c2=csub(a0,a2), c1=cadd(a1,a3), c3=cw2(csub(a1,a3));
    float2 d0=cadd(b0,b2), d2=csub(b0,b2), d1=cadd(b1,b3), d3=cw2(csub(b1,b3));
    v[0]=cadd(c0,c1); v[1]=csub(c0,c1);   // U0, U4
    v[2]=cadd(c2,c3); v[3]=csub(c2,c3);   // U2, U6
    v[4]=cadd(d0,d1); v[5]=csub(d0,d1);   // U1, U5
    v[6]=cadd(d2,d3); v[7]=csub(d2,d3);   // U3, U7
}

// Stockham radix-8 stage store: address-slot c gets U_c * w1^c at base+step*c.
__device__ __forceinline__ void stage_store(float2* wl, const float2* v, float2 w1,
                                            int base, int step){
    constexpr int br[8] = {0,4,2,6,1,5,3,7};
    wl[LADDR(base)] = v[0];
    float2 p = w1;
    #pragma unroll
    for (int c = 1; c < 8; ++c) {
        wl[LADDR(base + step*c)] = cmul(v[br[c]], p);
        p = cmul(p, w1);
    }
}

__device__ __forceinline__ void stage_load(const float2* wl, float2* v, int j){
    #pragma unroll
    for (int i = 0; i < 8; ++i) v[i] = wl[LADDR(j + 64*i)];
}

// ---------------- sector map (matches reference _polar_masks) ----------------
__device__ __forceinline__ int sector_id(int hm, int wm) {
    const float step = 2.0f / 511.0f;
    float y = -1.0f + step * (float)hm;
    float x = -1.0f + step * (float)wm;
    float radius = sqrtf(x * x + y * y);
    float r = radius / sqrtf(2.0f);
    float a = atan2f(y, x);
    a = fmodf(a, PI_F);
    if (a < 0.0f) a += PI_F;

    const float rstep = (0.9f - 0.08f) / 3.0f;
    const float re0 = 0.08f;
    const float re1 = 0.08f + rstep;
    const float re2 = 0.08f + 2.0f * rstep;
    const float re3 = 0.9f;
    int rb;
    if      (r >= re0 && r < re1)  rb = 0;
    else if (r >= re1 && r < re2)  rb = 1;
    else if (r >= re2 && r <= re3) rb = 2;
    else return -1;

    const float astep = PI_F / 8.0f;
    int ab = 7;
    #pragma unroll
    for (int i = 0; i < 7; ++i) {
        float t0 = astep * (float)i;
        float t1 = astep * (float)(i + 1);
        if (a >= t0 && a < t1) { ab = i; break; }
    }
    return rb * 8 + ab;
}

__device__ __forceinline__ float hannf(int i) {
    return 0.5f * (1.0f - __cosf(TWO_PI_F * (float)i / 511.0f));
}

// ---------------- kernel 1: luma + window + row FFT (radix-8 wave-sync) -------
// Block = 4 waves; each wave FFTs one packed row-pair (h0 real, h1 imag).
// NEW vs prev round:
//  * counts -> contention-free per-block uchar partials (was 2048-deep
//    same-address global fadd contention = the serialization stall)
//  * blocks 0..47 zero the 16x768 acc replicas (zero_kernel folded away)
//  * buf layout is 256 columns/img: k=0 slot packs the two REAL spectra
//    (k=0 DC, k=256 Nyquist) as (F0, F256) so colfft can pair-FFT them.
__global__ __launch_bounds__(256) void rowfft_kernel(const float* __restrict__ pred,
                                                     const float* __restrict__ tgt,
                                                     float4* __restrict__ out4,
                                                     unsigned char* __restrict__ mapT,
                                                     unsigned char* __restrict__ cnt_u8,
                                                     float* __restrict__ acc_rep) {
    __shared__ float2 lds[4 * 576];
    __shared__ float cbins[24];
    int blk = blockIdx.x;                 // 32 img * 64
    int img = blk >> 6;
    int pb  = blk & 63;
    int t = threadIdx.x;
    int wv = t >> 6, j = t & 63;
    int hp = pb * 4 + wv;                 // row-pair index [0,256)
    int h0 = 2 * hp;
    float2* wl = lds + wv * 576;

    if (blk < 48) acc_rep[blk * 256 + t] = 0.0f;   // zero 16*768 replica floats
    if (t < 24) cbins[t] = 0.0f;
    __syncthreads();
    if (t < 128) {                        // folded sector map + per-block counts
        int idx = blk * 128 + t;          // idx = wm*512 + hm
        int wm = idx >> 9, hm = idx & 511;
        int s = sector_id(hm, wm);
        mapT[idx] = (unsigned char)(s < 0 ? 255 : s);
        if (s >= 0) atomicAdd(&cbins[s], 1.0f);
    }

    const float* base = (img < 16) ? (pred + (size_t)img * 786432)
                                   : (tgt  + (size_t)(img - 16) * 786432);
    float wh0 = hannf(h0), wh1 = hannf(h0 + 1);
    float2 v[8];
    #pragma unroll
    for (int i = 0; i < 8; ++i) {
        int w = j + 64 * i;
        float ww = hannf(w);
        size_t off0 = (size_t)h0 * 512 + w;
        size_t off1 = off0 + 512;
        float l0 = 0.2989f*base[off0] + 0.587f*base[off0+262144] + 0.114f*base[off0+524288];
        float l1 = 0.2989f*base[off1] + 0.587f*base[off1+262144] + 0.114f*base[off1+524288];
        v[i] = make_float2(l0 * (wh0 * ww), l1 * (wh1 * ww));
    }
    float sn, cs;
    // stage 0: s=1, p=j, write 8j+c
    dft8(v);
    __sincosf(-TWO_PI_F * (float)j / 512.0f, &sn, &cs);
    stage_store(wl, v, make_float2(cs, sn), 8 * j, 1);
    WAVE_SYNC();
    // stage 1: s=8, q=j&7, p=j>>3, write q+64p+8c, twiddle W^{8p*c}
    stage_load(wl, v, j);
    WAVE_SYNC();
    dft8(v);
    __sincosf(-TWO_PI_F * (float)((j >> 3) << 3) / 512.0f, &sn, &cs);
    stage_store(wl, v, make_float2(cs, sn), (j & 7) + 64 * (j >> 3), 8);
    WAVE_SYNC();
    // stage 2: s=64, p=0 -> no twiddle; result in regs: Z[j+64c] = v[br[c]]
    stage_load(wl, v, j);
    dft8(v);
    constexpr int br[8] = {0,4,2,6,1,5,3,7};
    size_t kbase = (size_t)img * 256;
    int partner = (64 - j) & 63;
    // Hermitian unpack: Z[512-k]: lane 64-j slot 7-c (j>0) / lane 0 slot (8-c)&7 (j==0)
    #pragma unroll
    for (int c = 0; c < 4; ++c) {
        float2 zk = v[br[c]];
        float mx = __shfl(v[br[7 - c]].x, partner, 64);
        float my = __shfl(v[br[7 - c]].y, partner, 64);
        float2 zs = v[br[(8 - c) & 7]];
        float2 zm = make_float2(j == 0 ? zs.x : mx, j == 0 ? zs.y : my);
        int k = j + 64 * c;
        float4 o = make_float4(0.5f*(zk.x+zm.x), 0.5f*(zk.y-zm.y),
                               0.5f*(zk.y+zm.y), 0.5f*(zm.x-zk.x));
        if (k != 0) out4[(kbase + (size_t)k) * 256 + hp] = o;
    }
    if (j == 0) {                         // packed real pair: (F_h[0], F_h[256])
        float2 z0 = v[br[0]], z4 = v[br[4]];   // Z[0], Z[256] (both components real spectra)
        out4[kbase * 256 + hp] = make_float4(z0.x, z4.x, z0.y, z4.y);
    }
    __syncthreads();
    if (t < 24) cnt_u8[t * 2048 + blk] = (unsigned char)(int)cbins[t];  // <=128 fits u8
}

// ---------------- kernel 2: column FFT + log-mag + sector bins ----------------
// One wave per (img, widx), widx in [0,256): widx>=1 is column w=widx with
// Hermitian mirror covering [257,511]; widx==0 is the PACKED pair of real
// columns w=0 & w=256 (two real FFTs in one complex FFT, unpacked per k).
// Bin replicas alias the dead FFT scratch (LDS 18432B -> 8 blocks/CU).
// Per-wave sums go to 16 replica accumulators (contention 257 -> 16).
__global__ __launch_bounds__(256, 8) void colfft_kernel(const float2* __restrict__ buf,
                                                        const unsigned char* __restrict__ mapT,
                                                        float* __restrict__ acc_rep) {
    __shared__ float2 lds[4 * 576];
    int t = threadIdx.x;
    int wv = t >> 6, j = t & 63;
    int gid = blockIdx.x * 4 + wv;        // 0 .. 8191
    int img = gid >> 8;
    int widx = gid & 255;
    float2* wl = lds + wv * 576;

    const float2* col = buf + (size_t)gid * 512;
    float2 v[8];
    #pragma unroll
    for (int i = 0; i < 8; ++i) v[i] = col[j + 64 * i];

    // hoisted sector-map loads: addresses known at entry, latency hides under FFT
    bool pairw = (widx == 0);
    const unsigned char* mwA = mapT + (size_t)(pairw ? 256 : ((widx + 256) & 511)) * 512;
    const unsigned char* mwB = mapT + (size_t)(pairw ? 0   : ((256 - widx) & 511)) * 512;
    unsigned char sA[8], sB[8];
    #pragma unroll
    for (int c = 0; c < 8; ++c) {
        int hm = j + 64 * ((c + 4) & 7);              // (h+256)&511
        sA[c] = mwA[hm];
        int hm2 = pairw ? hm : ((256 - (j + 64 * c)) & 511);
        sB[c] = mwB[hm2];
    }

    float sn, cs;
    dft8(v);
    __sincosf(-TWO_PI_F * (float)j / 512.0f, &sn, &cs);
    stage_store(wl, v, make_float2(cs, sn), 8 * j, 1);
    WAVE_SYNC();
    stage_load(wl, v, j);
    WAVE_SYNC();
    dft8(v);
    __sincosf(-TWO_PI_F * (float)((j >> 3) << 3) / 512.0f, &sn, &cs);
    stage_store(wl, v, make_float2(cs, sn), (j & 7) + 64 * (j >> 3), 8);
    WAVE_SYNC();
    stage_load(wl, v, j);
    dft8(v);
    WAVE_SYNC();                          // FFT scratch now dead -> reuse as bins
    float* wb = (float*)wl;               // 200 floats: 8 bank-spread replicas x 25
    #pragma unroll
    for (int i = 0; i < 4; ++i) { int ii = j + 64 * i; if (ii < 200) wb[ii] = 0.0f; }
    WAVE_SYNC();

    constexpr int br[8] = {0,4,2,6,1,5,3,7};
    int rep = (j & 7) * 25;               // 25*r mod 32 distinct for r in [0,8)
    if (pairw) {
        // unpack two real-column FFTs: F0[k]=(Z[k]+conj(Z[-k]))/2,
        // F256[k]=(Z[k]-conj(Z[-k]))/(2i); Z[-k] via partner lane/slot.
        int partner = (64 - j) & 63;
        #pragma unroll
        for (int c = 0; c < 8; ++c) {
            float2 zk = v[br[c]];
            float mx = __shfl(v[br[7 - c]].x, partner, 64);
            float my = __shfl(v[br[7 - c]].y, partner, 64);
            float2 zs = v[br[(8 - c) & 7]];
            float2 zm = make_float2(j == 0 ? zs.x : mx, j == 0 ? zs.y : my);
            float f0x = 0.5f*(zk.x+zm.x), f0y = 0.5f*(zk.y-zm.y);
            float f1x = 0.5f*(zk.y+zm.y), f1y = 0.5f*(zm.x-zk.x);
            float mag0 = log1pf(sqrtf(f0x*f0x + f0y*f0y));   // column w=0   (wm=256)
            float mag1 = log1pf(sqrtf(f1x*f1x + f1y*f1y));   // column w=256 (wm=0)
            int s1 = sA[c]; if (s1 < 24) atomicAdd(&wb[rep + s1], mag0);
            int s2 = sB[c]; if (s2 < 24) atomicAdd(&wb[rep + s2], mag1);
        }
    } else {
        #pragma unroll
        for (int c = 0; c < 8; ++c) {
            float2 z = v[br[c]];          // Z[h = j + 64c]
            float mag = log1pf(sqrtf(z.x * z.x + z.y * z.y));
            int s1 = sA[c]; if (s1 < 24) atomicAdd(&wb[rep + s1], mag);
            int s2 = sB[c]; if (s2 < 24) atomicAdd(&wb[rep + s2], mag);  // mirror column
        }
    }
    WAVE_SYNC();
    if (j < 24) {
        float sum = 0.0f;
        #pragma unroll
        for (int r = 0; r < 8; ++r) sum += wb[r * 25 + j];
        // 16-way replica spread: per-address contention 256/img -> 16
        atomicAdd(&acc_rep[(gid & 15) * 768 + img * 24 + j], sum);
    }
}

// ---------------- kernel 3: reduce replicas/partials -> loss ----------------
__global__ __launch_bounds__(256) void final_kernel(const float* __restrict__ acc_rep,
                                                    const unsigned char* __restrict__ cnt_u8,
                                                    const float* __restrict__ rw,
                                                    float* __restrict__ out) {
    __shared__ float accs[768];
    __shared__ float cnts[24];
    __shared__ float ep[384], et[384], red[384];
    int t = threadIdx.x;
    for (int o = t; o < 768; o += 256) {           // sum 16 replicas (coalesced)
        float s = 0.0f;
        #pragma unroll
        for (int r = 0; r < 16; ++r) s += acc_rep[r * 768 + o];
        accs[o] = s;
    }
    if (t < 192) {                                 // counts: 24 sectors x 8 lanes
        int s = t >> 3, g = t & 7;
        const uchar4* p = (const uchar4*)(cnt_u8 + s * 2048 + g * 256);
        float sum = 0.0f;
        #pragma unroll
        for (int i = 0; i < 64; ++i) { uchar4 u = p[i]; sum += (float)(u.x + u.y + u.z + u.w); }
        sum += __shfl_down(sum, 4, 8);
        sum += __shfl_down(sum, 2, 8);
        sum += __shfl_down(sum, 1, 8);
        if (g == 0) cnts[s] = sum;
    }
    __syncthreads();
    for (int idx = t; idx < 384; idx += 256) {     // idx = b*24 + s, b in [0,16)
        int b = idx / 24, s = idx - b * 24;
        float cnt = fmaxf(cnts[s], 1e-6f);
        ep[idx] = accs[b * 24 + s] / cnt;
        et[idx] = accs[(16 + b) * 24 + s] / cnt;
    }
    __syncthreads();
    for (int idx = t; idx < 384; idx += 256) {
        int b = idx / 24, s = idx - b * 24, r = s >> 3;
        int gbase = b * 24 + r * 8;
        float sp = 0.0f, st = 0.0f;
        #pragma unroll
        for (int a = 0; a < 8; ++a) { sp += ep[gbase + a]; st += et[gbase + a]; }
        float pe = ep[idx] / fmaxf(sp, 1e-6f);
        float te = et[idx] / fmaxf(st, 1e-6f);
        float d = pe - te;
        red[idx] = sqrtf(d * d + 1e-6f) * rw[r];
    }
    __syncthreads();
    if (t < 128) red[t] += red[t + 128] + red[t + 256];
    __syncthreads();
    if (t < 64) {
        float vv = red[t] + red[t + 64];
        #pragma unroll
        for (int o = 32; o > 0; o >>= 1) vv += __shfl_down(vv, o, 64);
        if (t == 0) out[0] = vv / 384.0f;
    }
}

extern "C" void kernel_launch(void* const* d_in, const int* in_sizes, int n_in,
                              void* d_out, int out_size, void* d_ws, size_t ws_size,
                              hipStream_t stream) {
    const float* pred = (const float*)d_in[0];
    const float* tgt  = (const float*)d_in[1];
    const float* rw   = (const float*)d_in[2];

    char* ws = (char*)d_ws;
    float* acc_rep      = (float*)ws;                     // 16*768 floats = 49152 B
    unsigned char* cnt  = (unsigned char*)(ws + 49152);   // 24*2048       = 49152 B
    unsigned char* mapT = (unsigned char*)(ws + 98304);   // 512*512       = 262144 B
    float2* buf         = (float2*)(ws + 360448);         // 32*256*512*8  = 33.55 MB
    // total 33,914,880 B (under previous round's 33,951,744 B footprint)

    rowfft_kernel<<<2048, 256, 0, stream>>>(pred, tgt, (float4*)buf, mapT, cnt, acc_rep);
    colfft_kernel<<<2048, 256, 0, stream>>>(buf, mapT, acc_rep);
    final_kernel<<<1, 256, 0, stream>>>(acc_rep, cnt, rw, (float*)d_out);
}

// Round 2
// 194.272 us; speedup vs baseline: 1.0578x; 1.0467x over previous
//
#include <hip/hip_runtime.h>
#include <math.h>

#define PI_F 3.14159265358979323846f
#define TWO_PI_F 6.28318530717958647692f
#define RSQ2 0.70710678118654752440f

// counted DS waits: DS ops retire in issue order within a wave, so
// lgkmcnt(8) after issuing 8 younger ops proves all older DS ops are done.
#define LGKM(n) __asm__ volatile("s_waitcnt lgkmcnt(" #n ")" ::: "memory")
// additive swizzle: injective on [0,512), max 574; breaks the 2-bank
// degeneracy of the stage-0 write pattern (8j+i).
#define LADDR(a) ((a) + ((a) >> 3))

__device__ __forceinline__ float2 cadd(float2 a, float2 b){ return make_float2(a.x+b.x, a.y+b.y); }
__device__ __forceinline__ float2 csub(float2 a, float2 b){ return make_float2(a.x-b.x, a.y-b.y); }
__device__ __forceinline__ float2 cmul(float2 a, float2 b){ return make_float2(a.x*b.x - a.y*b.y, a.x*b.y + a.y*b.x); }
__device__ __forceinline__ float2 cw1(float2 a){ return make_float2(RSQ2*(a.x+a.y), RSQ2*(a.y-a.x)); }  // *W8^1
__device__ __forceinline__ float2 cw2(float2 a){ return make_float2(a.y, -a.x); }                        // *(-i)
__device__ __forceinline__ float2 cw3(float2 a){ return make_float2(RSQ2*(a.y-a.x), -RSQ2*(a.x+a.y)); }  // *W8^3

// in-place DIF-8. On return, slot m holds U_{br[m]}, br = {0,4,2,6,1,5,3,7}.
__device__ __forceinline__ void dft8(float2* v){
    float2 a0=cadd(v[0],v[4]), a1=cadd(v[1],v[5]), a2=cadd(v[2],v[6]), a3=cadd(v[3],v[7]);
    float2 b0=csub(v[0],v[4]);
    float2 b1=cw1(csub(v[1],v[5]));
    float2 b2=cw2(csub(v[2],v[6]));
    float2 b3=cw3(csub(v[3],v[7]));
    float2 c0=cadd(a0,a2), c2=csub(a0,a2), c1=cadd(a1,a3), c3=cw2(csub(a1,a3));
    float2 d0=cadd(b0,b2), d2=csub(b0,b2), d1=cadd(b1,b3), d3=cw2(csub(b1,b3));
    v[0]=cadd(c0,c1); v[1]=csub(c0,c1);   // U0, U4
    v[2]=cadd(c2,c3); v[3]=csub(c2,c3);   // U2, U6
    v[4]=cadd(d0,d1); v[5]=csub(d0,d1);   // U1, U5
    v[6]=cadd(d2,d3); v[7]=csub(d2,d3);   // U3, U7
}

// twiddle powers w^1..w^7 via log-depth tree (computed once, reused by both streams)
__device__ __forceinline__ void calc_pows(float2 w, float2* p){
    p[0] = w;
    p[1] = cmul(w, w);          // w^2
    p[2] = cmul(p[1], w);       // w^3
    p[3] = cmul(p[1], p[1]);    // w^4
    p[4] = cmul(p[2], p[1]);    // w^5
    p[5] = cmul(p[2], p[2]);    // w^6
    p[6] = cmul(p[3], p[2]);    // w^7
}

// Stockham radix-8 stage store: address-slot c gets U_c * w^c at base+step*c.
__device__ __forceinline__ void stage_store(float2* wl, const float2* v, const float2* p,
                                            int base, int step){
    constexpr int br[8] = {0,4,2,6,1,5,3,7};
    wl[LADDR(base)] = v[0];
    #pragma unroll
    for (int c = 1; c < 8; ++c) wl[LADDR(base + step*c)] = cmul(v[br[c]], p[c-1]);
}

__device__ __forceinline__ void stage_load(const float2* wl, float2* v, int j){
    #pragma unroll
    for (int i = 0; i < 8; ++i) v[i] = wl[LADDR(j + 64*i)];
}

// ---------------- sector map (matches reference _polar_masks) ----------------
__device__ __forceinline__ int sector_id(int hm, int wm) {
    const float step = 2.0f / 511.0f;
    float y = -1.0f + step * (float)hm;
    float x = -1.0f + step * (float)wm;
    float radius = sqrtf(x * x + y * y);
    float r = radius / sqrtf(2.0f);
    float a = atan2f(y, x);
    a = fmodf(a, PI_F);
    if (a < 0.0f) a += PI_F;

    const float rstep = (0.9f - 0.08f) / 3.0f;
    const float re0 = 0.08f;
    const float re1 = 0.08f + rstep;
    const float re2 = 0.08f + 2.0f * rstep;
    const float re3 = 0.9f;
    int rb;
    if      (r >= re0 && r < re1)  rb = 0;
    else if (r >= re1 && r < re2)  rb = 1;
    else if (r >= re2 && r <= re3) rb = 2;
    else return -1;

    const float astep = PI_F / 8.0f;
    int ab = 7;
    #pragma unroll
    for (int i = 0; i < 7; ++i) {
        float t0 = astep * (float)i;
        float t1 = astep * (float)(i + 1);
        if (a >= t0 && a < t1) { ab = i; break; }
    }
    return rb * 8 + ab;
}

__device__ __forceinline__ float hannf(int i) {
    return 0.5f * (1.0f - __cosf(TWO_PI_F * (float)i / 511.0f));
}

__device__ __forceinline__ float lumaf(const float* b, size_t off){
    return 0.2989f*b[off] + 0.587f*b[off+262144] + 0.114f*b[off+524288];
}

// ---------------- kernel 1: luma + window + row FFT (2 FFTs/wave pipelined) ---
// Block = 4 waves; each wave FFTs TWO packed row-pairs (A: rows h0,h0+1 and
// B: rows h0+2,h0+3) with counted-lgkm software pipelining so stream B's DS
// latency hides under stream A's compute and vice versa.
__global__ __launch_bounds__(256, 4) void rowfft_kernel(const float* __restrict__ pred,
                                                        const float* __restrict__ tgt,
                                                        float4* __restrict__ out4,
                                                        unsigned char* __restrict__ mapT,
                                                        unsigned short* __restrict__ cnt_u16,
                                                        float* __restrict__ acc_rep) {
    __shared__ float2 lds[4 * 1152];
    __shared__ float cbins[24];
    int blk = blockIdx.x;                 // 32 img * 32
    int img = blk >> 5;
    int pb  = blk & 31;
    int t = threadIdx.x;
    int wv = t >> 6, j = t & 63;
    int hpA = pb * 8 + wv * 2;            // row-pair indices [0,256)
    int hpB = hpA + 1;
    int h0 = 2 * hpA;                     // rows h0..h0+3
    float2* wlA = lds + wv * 1152;
    float2* wlB = wlA + 576;

    if (blk < 48) acc_rep[blk * 256 + t] = 0.0f;   // zero 16*768 replica floats
    if (t < 24) cbins[t] = 0.0f;
    __syncthreads();
    {                                     // folded sector map + per-block counts
        int idx = blk * 256 + t;          // idx = wm*512 + hm ; 1024*256 = full map
        int wm = idx >> 9, hm = idx & 511;
        int s = sector_id(hm, wm);
        mapT[idx] = (unsigned char)(s < 0 ? 255 : s);
        if (s >= 0) atomicAdd(&cbins[s], 1.0f);
    }

    const float* base = (img < 16) ? (pred + (size_t)img * 786432)
                                   : (tgt  + (size_t)(img - 16) * 786432);
    float whA0 = hannf(h0), whA1 = hannf(h0 + 1);
    float whB0 = hannf(h0 + 2), whB1 = hannf(h0 + 3);
    float2 va[8], vb[8];
    #pragma unroll
    for (int i = 0; i < 8; ++i) {
        int w = j + 64 * i;
        float ww = hannf(w);
        size_t off0 = (size_t)h0 * 512 + w;
        float l0 = lumaf(base, off0);
        float l1 = lumaf(base, off0 + 512);
        float l2 = lumaf(base, off0 + 1024);
        float l3 = lumaf(base, off0 + 1536);
        va[i] = make_float2(l0 * (whA0 * ww), l1 * (whA1 * ww));
        vb[i] = make_float2(l2 * (whB0 * ww), l3 * (whB1 * ww));
    }

    float sn, cs;
    __sincosf(-TWO_PI_F * (float)j / 512.0f, &sn, &cs);
    float2 tw0 = make_float2(cs, sn);
    __sincosf(-TWO_PI_F * (float)((j >> 3) << 3) / 512.0f, &sn, &cs);
    float2 tw1 = make_float2(cs, sn);
    float2 pw[7];

    // ---- pipelined 3-stage Stockham radix-8, two independent streams ----
    calc_pows(tw0, pw);
    dft8(va);
    dft8(vb);
    stage_store(wlA, va, pw, 8 * j, 1);
    stage_store(wlB, vb, pw, 8 * j, 1);
    LGKM(8);                              // A writes done
    stage_load(wlA, va, j);
    LGKM(8);                              // B writes done
    stage_load(wlB, vb, j);
    LGKM(8);                              // A reads done (B reads in flight)
    calc_pows(tw1, pw);
    dft8(va);
    stage_store(wlA, va, pw, (j & 7) + 64 * (j >> 3), 8);
    LGKM(8);                              // B reads done (A writes in flight)
    dft8(vb);
    stage_store(wlB, vb, pw, (j & 7) + 64 * (j >> 3), 8);
    LGKM(8);                              // A writes done
    stage_load(wlA, va, j);
    LGKM(8);                              // B writes done
    stage_load(wlB, vb, j);
    LGKM(8);                              // A reads done (B reads in flight)
    dft8(va);
    LGKM(0);                              // B reads done
    dft8(vb);

    constexpr int br[8] = {0,4,2,6,1,5,3,7};
    size_t kbase = (size_t)img * 256;
    int partner = (64 - j) & 63;
    // Hermitian unpack: Z[512-k]: lane 64-j slot 7-c (j>0) / lane 0 slot (8-c)&7 (j==0)
    #pragma unroll
    for (int c = 0; c < 4; ++c) {
        int k = j + 64 * c;
        // stream A
        float2 zk = va[br[c]];
        float mx = __shfl(va[br[7 - c]].x, partner, 64);
        float my = __shfl(va[br[7 - c]].y, partner, 64);
        float2 zs = va[br[(8 - c) & 7]];
        float2 zm = make_float2(j == 0 ? zs.x : mx, j == 0 ? zs.y : my);
        float4 o = make_float4(0.5f*(zk.x+zm.x), 0.5f*(zk.y-zm.y),
                               0.5f*(zk.y+zm.y), 0.5f*(zm.x-zk.x));
        if (k != 0) out4[(kbase + (size_t)k) * 256 + hpA] = o;
        // stream B
        zk = vb[br[c]];
        mx = __shfl(vb[br[7 - c]].x, partner, 64);
        my = __shfl(vb[br[7 - c]].y, partner, 64);
        zs = vb[br[(8 - c) & 7]];
        zm = make_float2(j == 0 ? zs.x : mx, j == 0 ? zs.y : my);
        o = make_float4(0.5f*(zk.x+zm.x), 0.5f*(zk.y-zm.y),
                        0.5f*(zk.y+zm.y), 0.5f*(zm.x-zk.x));
        if (k != 0) out4[(kbase + (size_t)k) * 256 + hpB] = o;
    }
    if (j == 0) {                         // packed real pair: (F_h[0], F_h[256])
        float2 z0 = va[br[0]], z4 = va[br[4]];
        out4[kbase * 256 + hpA] = make_float4(z0.x, z4.x, z0.y, z4.y);
        z0 = vb[br[0]]; z4 = vb[br[4]];
        out4[kbase * 256 + hpB] = make_float4(z0.x, z4.x, z0.y, z4.y);
    }
    __syncthreads();
    if (t < 24) cnt_u16[t * 1024 + blk] = (unsigned short)(int)cbins[t];
}

// ---------------- kernel 2: column FFT + log-mag + sector bins ----------------
// Each wave handles TWO adjacent columns (gid 2p, 2p+1 — same img since 256|2),
// software-pipelined as in rowfft. widx==0 (stream A of pair 0 mod 128) is the
// PACKED pair of real columns w=0 & w=256. Bin replicas alias dead FFT scratch;
// one global-atomic set per wave covers both columns.
__global__ __launch_bounds__(256, 4) void colfft_kernel(const float2* __restrict__ buf,
                                                        const unsigned char* __restrict__ mapT,
                                                        float* __restrict__ acc_rep) {
    __shared__ float2 lds[4 * 1152];
    int t = threadIdx.x;
    int wv = t >> 6, j = t & 63;
    int pg = blockIdx.x * 4 + wv;         // pair id 0..4095
    int gidA = pg * 2;
    int img = pg >> 7;
    int wA = gidA & 255, wB = wA + 1;     // wA even, wB odd in [1,255]
    float2* wlA = lds + wv * 1152;
    float2* wlB = wlA + 576;

    const float2* colA = buf + (size_t)gidA * 512;
    float2 va[8], vb[8];
    #pragma unroll
    for (int i = 0; i < 8; ++i) va[i] = colA[j + 64 * i];
    #pragma unroll
    for (int i = 0; i < 8; ++i) vb[i] = colA[512 + j + 64 * i];

    // hoisted sector-map loads: latency hides under the FFT
    bool pairw = (wA == 0);
    const unsigned char* mwA1 = mapT + (size_t)(pairw ? 256 : ((wA + 256) & 511)) * 512;
    const unsigned char* mwA2 = mapT + (size_t)(pairw ? 0   : ((256 - wA) & 511)) * 512;
    const unsigned char* mwB1 = mapT + (size_t)((wB + 256) & 511) * 512;
    const unsigned char* mwB2 = mapT + (size_t)((256 - wB) & 511) * 512;
    unsigned char sA1[8], sA2[8], sB1[8], sB2[8];
    #pragma unroll
    for (int c = 0; c < 8; ++c) {
        int hm = j + 64 * ((c + 4) & 7);              // (h+256)&511
        int hm2 = (256 - (j + 64 * c)) & 511;
        sA1[c] = mwA1[hm];
        sA2[c] = pairw ? mwA2[hm] : mwA2[hm2];
        sB1[c] = mwB1[hm];
        sB2[c] = mwB2[hm2];
    }

    float sn, cs;
    __sincosf(-TWO_PI_F * (float)j / 512.0f, &sn, &cs);
    float2 tw0 = make_float2(cs, sn);
    __sincosf(-TWO_PI_F * (float)((j >> 3) << 3) / 512.0f, &sn, &cs);
    float2 tw1 = make_float2(cs, sn);
    float2 pw[7];

    calc_pows(tw0, pw);
    dft8(va);
    dft8(vb);
    stage_store(wlA, va, pw, 8 * j, 1);
    stage_store(wlB, vb, pw, 8 * j, 1);
    LGKM(8);                              // A writes done
    stage_load(wlA, va, j);
    LGKM(8);                              // B writes done
    stage_load(wlB, vb, j);
    LGKM(8);                              // A reads done (B reads in flight)
    calc_pows(tw1, pw);
    dft8(va);
    stage_store(wlA, va, pw, (j & 7) + 64 * (j >> 3), 8);
    LGKM(8);                              // B reads done (A writes in flight)
    dft8(vb);
    stage_store(wlB, vb, pw, (j & 7) + 64 * (j >> 3), 8);
    LGKM(8);                              // A writes done
    stage_load(wlA, va, j);
    LGKM(8);                              // B writes done
    stage_load(wlB, vb, j);
    LGKM(8);                              // A reads done (B reads in flight)
    dft8(va);
    LGKM(0);                              // B reads done
    dft8(vb);

    float* wb = (float*)wlA;              // FFT scratch dead -> 8 replicas x 25 bins
    #pragma unroll
    for (int i = 0; i < 4; ++i) { int ii = j + 64 * i; if (ii < 200) wb[ii] = 0.0f; }
    LGKM(0);

    constexpr int br[8] = {0,4,2,6,1,5,3,7};
    int rep = (j & 7) * 25;               // 25*r mod 32 distinct for r in [0,8)
    if (pairw) {
        // unpack two real-column FFTs: F0[k]=(Z[k]+conj(Z[-k]))/2,
        // F256[k]=(Z[k]-conj(Z[-k]))/(2i)
        int partner = (64 - j) & 63;
        #pragma unroll
        for (int c = 0; c < 8; ++c) {
            float2 zk = va[br[c]];
            float mx = __shfl(va[br[7 - c]].x, partner, 64);
            float my = __shfl(va[br[7 - c]].y, partner, 64);
            float2 zs = va[br[(8 - c) & 7]];
            float2 zm = make_float2(j == 0 ? zs.x : mx, j == 0 ? zs.y : my);
            float f0x = 0.5f*(zk.x+zm.x), f0y = 0.5f*(zk.y-zm.y);
            float f1x = 0.5f*(zk.y+zm.y), f1y = 0.5f*(zm.x-zk.x);
            float mag0 = __logf(1.0f + sqrtf(f0x*f0x + f0y*f0y));   // col w=0
            float mag1 = __logf(1.0f + sqrtf(f1x*f1x + f1y*f1y));   // col w=256
            int s1 = sA1[c]; if (s1 < 24) atomicAdd(&wb[rep + s1], mag0);
            int s2 = sA2[c]; if (s2 < 24) atomicAdd(&wb[rep + s2], mag1);
        }
    } else {
        #pragma unroll
        for (int c = 0; c < 8; ++c) {
            float2 z = va[br[c]];         // wA in [2,254] -> mirror always valid
            float mag = __logf(1.0f + sqrtf(z.x * z.x + z.y * z.y));
            int s1 = sA1[c]; if (s1 < 24) atomicAdd(&wb[rep + s1], mag);
            int s2 = sA2[c]; if (s2 < 24) atomicAdd(&wb[rep + s2], mag);
        }
    }
    #pragma unroll
    for (int c = 0; c < 8; ++c) {         // stream B: wB in [1,255], always mirrored
        float2 z = vb[br[c]];
        float mag = __logf(1.0f + sqrtf(z.x * z.x + z.y * z.y));
        int s1 = sB1[c]; if (s1 < 24) atomicAdd(&wb[rep + s1], mag);
        int s2 = sB2[c]; if (s2 < 24) atomicAdd(&wb[rep + s2], mag);
    }
    LGKM(0);
    if (j < 24) {
        float sum = 0.0f;
        #pragma unroll
        for (int r = 0; r < 8; ++r) sum += wb[r * 25 + j];
        atomicAdd(&acc_rep[(pg & 15) * 768 + img * 24 + j], sum);
    }
}

// ---------------- kernel 3: reduce replicas/partials -> loss ----------------
__global__ __launch_bounds__(256) void final_kernel(const float* __restrict__ acc_rep,
                                                    const unsigned short* __restrict__ cnt_u16,
                                                    const float* __restrict__ rw,
                                                    float* __restrict__ out) {
    __shared__ float accs[768];
    __shared__ float cnts[24];
    __shared__ float ep[384], et[384], red[384];
    int t = threadIdx.x;
    for (int o = t; o < 768; o += 256) {           // sum 16 replicas (coalesced)
        float s = 0.0f;
        #pragma unroll
        for (int r = 0; r < 16; ++r) s += acc_rep[r * 768 + o];
        accs[o] = s;
    }
    if (t < 192) {                                 // counts: 24 sectors x 8 lanes
        int s = t >> 3, g = t & 7;
        const ushort4* p = (const ushort4*)(cnt_u16 + s * 1024 + g * 128);
        float sum = 0.0f;
        #pragma unroll
        for (int i = 0; i < 32; ++i) { ushort4 u = p[i]; sum += (float)(u.x + u.y + u.z + u.w); }
        sum += __shfl_down(sum, 4, 8);
        sum += __shfl_down(sum, 2, 8);
        sum += __shfl_down(sum, 1, 8);
        if (g == 0) cnts[s] = sum;
    }
    __syncthreads();
    for (int idx = t; idx < 384; idx += 256) {     // idx = b*24 + s, b in [0,16)
        int b = idx / 24, s = idx - b * 24;
        float cnt = fmaxf(cnts[s], 1e-6f);
        ep[idx] = accs[b * 24 + s] / cnt;
        et[idx] = accs[(16 + b) * 24 + s] / cnt;
    }
    __syncthreads();
    for (int idx = t; idx < 384; idx += 256) {
        int b = idx / 24, s = idx - b * 24, r = s >> 3;
        int gbase = b * 24 + r * 8;
        float sp = 0.0f, st = 0.0f;
        #pragma unroll
        for (int a = 0; a < 8; ++a) { sp += ep[gbase + a]; st += et[gbase + a]; }
        float pe = ep[idx] / fmaxf(sp, 1e-6f);
        float te = et[idx] / fmaxf(st, 1e-6f);
        float d = pe - te;
        red[idx] = sqrtf(d * d + 1e-6f) * rw[r];
    }
    __syncthreads();
    if (t < 128) red[t] += red[t + 128] + red[t + 256];
    __syncthreads();
    if (t < 64) {
        float vv = red[t] + red[t + 64];
        #pragma unroll
        for (int o = 32; o > 0; o >>= 1) vv += __shfl_down(vv, o, 64);
        if (t == 0) out[0] = vv / 384.0f;
    }
}

extern "C" void kernel_launch(void* const* d_in, const int* in_sizes, int n_in,
                              void* d_out, int out_size, void* d_ws, size_t ws_size,
                              hipStream_t stream) {
    const float* pred = (const float*)d_in[0];
    const float* tgt  = (const float*)d_in[1];
    const float* rw   = (const float*)d_in[2];

    char* ws = (char*)d_ws;
    float* acc_rep       = (float*)ws;                     // 16*768 floats = 49152 B
    unsigned short* cnt  = (unsigned short*)(ws + 49152);  // 24*1024*2     = 49152 B
    unsigned char* mapT  = (unsigned char*)(ws + 98304);   // 512*512       = 262144 B
    float2* buf          = (float2*)(ws + 360448);         // 32*256*512*8  = 33.55 MB

    rowfft_kernel<<<1024, 256, 0, stream>>>(pred, tgt, (float4*)buf, mapT, cnt, acc_rep);
    colfft_kernel<<<1024, 256, 0, stream>>>(buf, mapT, acc_rep);
    final_kernel<<<1, 256, 0, stream>>>(acc_rep, cnt, rw, (float*)d_out);
}